// Round 8
// baseline (156.940 us; speedup 1.0000x reference)
//
#include <hip/hip_runtime.h>
#include <hip/hip_cooperative_groups.h>
#include <hip/hip_bf16.h>

namespace cg = cooperative_groups;

#define SLEN 8192
#define EDIM 1024
#define NB   1024   // attention blocks; 8 positions per block (one per wave)

typedef float f4 __attribute__((ext_vector_type(4)));

// ---------------- helpers ----------------

// block-wide (256 thr) sum of (x, x2); result broadcast
__device__ inline float2 blockSum256_2(float2 v, float2* lds) {
#pragma unroll
    for (int off = 32; off; off >>= 1) {
        v.x += __shfl_xor(v.x, off);
        v.y += __shfl_xor(v.y, off);
    }
    int w = threadIdx.x >> 6, ln = threadIdx.x & 63;
    __syncthreads();
    if (ln == 0) lds[w] = v;
    __syncthreads();
    float2 s;
    s.x = lds[0].x + lds[1].x + lds[2].x + lds[3].x;
    s.y = lds[0].y + lds[1].y + lds[2].y + lds[3].y;
    return s;
}

// ---------------- QKV GEMV (split-K partials) ----------------
// grid (12, 16), block 256
__global__ __launch_bounds__(256) void qkv_partial(
    const float* __restrict__ Wq, const float* __restrict__ Wk,
    const float* __restrict__ Wv, const float* __restrict__ x,
    float* __restrict__ part) {
    int cg_ = blockIdx.x;
    int m = cg_ >> 2;
    const float* W = (m == 0) ? Wq : ((m == 1) ? Wk : Wv);
    int col = (cg_ & 3) * 256 + threadIdx.x;
    int r0 = blockIdx.y * 64;
    float acc = 0.f;
#pragma unroll 8
    for (int r = 0; r < 64; ++r)
        acc = fmaf(x[r0 + r], W[(r0 + r) * EDIM + col], acc);
    part[((size_t)m * 16 + blockIdx.y) * EDIM + col] = acc;
}

// ---------------- fused qkv-combine + cache-shift + attention ----------------
// grid NB, block 512 (8 waves). Wave w owns position s = blockIdx.x*8 + w.
// Prologue: every block rebuilds qs from the 16 q-partial slices (L2-hot);
// the last block also rebuilds ki/vi into an LDS alias of sacc.
__global__ __launch_bounds__(512) void attn_main(
    const float* __restrict__ cache,   // [2, S, 1024]
    const float* __restrict__ qkvp,    // [48][1024] partials (q:0-15, k:16-31, v:32-47)
    const float* __restrict__ bq, const float* __restrict__ bk,
    const float* __restrict__ bv,
    float* __restrict__ nv, float* __restrict__ nk,
    float* __restrict__ m2, float* __restrict__ l2, float* __restrict__ acc2) {
    __shared__ float qs_l[1024];
    __shared__ float sm[8][16];        // per-wave per-head scores
    __shared__ float mlM[16], mlL[16];
    __shared__ float sacc[8][16][64];  // 32 KB weighted V (first 2048 floats alias ki/vi)
    float* kivi = &sacc[0][0][0];      // [0..1023]=vi, [1024..2047]=ki

    int tid = threadIdx.x;
    int w = tid >> 6, ld = tid & 63;
    int s = blockIdx.x * 8 + w;

    // qs = (x@Wq + bq)/8 rebuilt from partials
#pragma unroll
    for (int j = 0; j < 2; ++j) {
        int c = tid + 512 * j;
        float v = bq[c];
#pragma unroll
        for (int sl = 0; sl < 16; ++sl) v += qkvp[sl * EDIM + c];
        qs_l[c] = v * 0.125f;
    }
    if (blockIdx.x == NB - 1) {
#pragma unroll
        for (int j = 0; j < 2; ++j) {
            int c = tid + 512 * j;
            float vv_ = bv[c], kk_ = bk[c];
#pragma unroll
            for (int sl = 0; sl < 16; ++sl) {
                vv_ += qkvp[(32 + sl) * EDIM + c];
                kk_ += qkvp[(16 + sl) * EDIM + c];
            }
            kivi[c] = vv_;
            kivi[1024 + c] = kk_;
        }
    }
    __syncthreads();

    bool last = (s >= SLEN - 1);
    f4 vv[4], kv[4], q4[4];
    if (!last) {
        const float* vsrc = cache + (size_t)(s + 1) * EDIM;
        const float* ksrc = cache + (size_t)(SLEN + s + 1) * EDIM;
#pragma unroll
        for (int it = 0; it < 4; ++it)
            vv[it] = __builtin_nontemporal_load((const f4*)(vsrc + it * 256 + ld * 4));
#pragma unroll
        for (int it = 0; it < 4; ++it)
            kv[it] = __builtin_nontemporal_load((const f4*)(ksrc + it * 256 + ld * 4));
    } else {
        // uniform branch for the whole wave; reads complete before barrier below,
        // and sacc (alias) is only written after the NEXT barrier -> safe.
#pragma unroll
        for (int it = 0; it < 4; ++it) {
            vv[it] = *(const f4*)&kivi[it * 256 + ld * 4];
            kv[it] = *(const f4*)&kivi[1024 + it * 256 + ld * 4];
        }
    }
#pragma unroll
    for (int it = 0; it < 4; ++it)
        q4[it] = *(const f4*)&qs_l[it * 256 + ld * 4];

    // V: store to new cache + bitwise nz
    unsigned nzb = 0u;
#pragma unroll
    for (int it = 0; it < 4; ++it) {
        __builtin_nontemporal_store(vv[it], (f4*)(nv + (size_t)s * EDIM + it * 256 + ld * 4));
        nzb |= __float_as_uint(vv[it].x) | __float_as_uint(vv[it].y) |
               __float_as_uint(vv[it].z) | __float_as_uint(vv[it].w);
    }
    // K: store + per-head dot (16-lane-group shfl reduce)
    float sc[4];
#pragma unroll
    for (int it = 0; it < 4; ++it) {
        __builtin_nontemporal_store(kv[it], (f4*)(nk + (size_t)s * EDIM + it * 256 + ld * 4));
        float d = q4[it].x * kv[it].x + q4[it].y * kv[it].y +
                  q4[it].z * kv[it].z + q4[it].w * kv[it].w;
        d += __shfl_xor(d, 1);
        d += __shfl_xor(d, 2);
        d += __shfl_xor(d, 4);
        d += __shfl_xor(d, 8);
        sc[it] = d;    // score for head it*4 + (ld>>4)
    }
    if (__ballot(nzb != 0u) == 0ull) {
#pragma unroll
        for (int it = 0; it < 4; ++it) sc[it] = -1e30f;
    }
    if ((ld & 15) == 0) {
#pragma unroll
        for (int it = 0; it < 4; ++it) sm[w][it * 4 + (ld >> 4)] = sc[it];
    }
    __syncthreads();

    // wave 0, lanes 0..15: per-head block max & partition sum (computed ONCE)
    if (tid < 16) {
        float M = sm[0][tid];
#pragma unroll
        for (int ww = 1; ww < 8; ++ww) M = fmaxf(M, sm[ww][tid]);
        float L = 0.f;
#pragma unroll
        for (int ww = 0; ww < 8; ++ww) L += __expf(sm[ww][tid] - M);
        mlM[tid] = M; mlL[tid] = L;
    }
    __syncthreads();

    // each thread: own weight only, write weighted V to LDS
#pragma unroll
    for (int it = 0; it < 4; ++it) {
        int h = it * 4 + (ld >> 4);
        float wg = __expf(sc[it] - mlM[h]);
        *(f4*)&sacc[w][h][(ld & 15) * 4] =
            (f4){wg * vv[it].x, wg * vv[it].y, wg * vv[it].z, wg * vv[it].w};
    }
    __syncthreads();

    // wave w reduces heads 2w, 2w+1 across the 8 waves; write block partial
#pragma unroll
    for (int j = 0; j < 2; ++j) {
        int h = 2 * w + j;
        float a = 0.f;
#pragma unroll
        for (int ww = 0; ww < 8; ++ww) a += sacc[ww][h][ld];
        acc2[((size_t)blockIdx.x * 16 + h) * 64 + ld] = a;
        if (ld == 0) {
            m2[blockIdx.x * 16 + h] = mlM[h];
            l2[blockIdx.x * 16 + h] = mlL[h];
        }
    }
}

// ---------------- cooperative tail: red -> Wo -> LN1+W1 -> ReLU+W2 -> LN2 ----
// grid 256, block 256 (4 waves). 4 grid syncs replace 5 kernel launches.
__global__ __launch_bounds__(256) void tail(
    const float* __restrict__ m2, const float* __restrict__ l2,
    const float* __restrict__ acc2,
    const float* __restrict__ Wo, const float* __restrict__ bo,
    const float* __restrict__ x,
    const float* __restrict__ ln1s, const float* __restrict__ ln1b,
    const float* __restrict__ W1, const float* __restrict__ b1,
    const float* __restrict__ W2, const float* __restrict__ b2,
    const float* __restrict__ ln2s, const float* __restrict__ ln2b,
    float* __restrict__ m3, float* __restrict__ l3, float* __restrict__ acc3,
    float* __restrict__ gp1, float* __restrict__ h1,
    float* __restrict__ gp2, float* __restrict__ gp3,
    float* __restrict__ out) {
    cg::grid_group grid = cg::this_grid();
    __shared__ float r_l[1024];
    __shared__ float sred[4][64];
    __shared__ float vals[64];
    __shared__ float sA[4][64];
    __shared__ float sM[4], sL[4];
    __shared__ float2 red[4];

    int b = blockIdx.x, t = threadIdx.x, w = t >> 6, ld = t & 63;

    // ---- stage A: level-1 softmax-partial reduce: (head, group) = (b>>4, b&15)
    {
        int h = b >> 4, g = b & 15;
        int p0 = g * 64 + w * 16;
        float mv[16];
#pragma unroll
        for (int i = 0; i < 16; ++i) mv[i] = m2[(p0 + i) * 16 + h];
        float lm = -1e30f;
#pragma unroll
        for (int i = 0; i < 16; ++i) lm = fmaxf(lm, mv[i]);
        float ll = 0.f, la = 0.f;
#pragma unroll
        for (int i = 0; i < 16; ++i) {
            float e = __expf(mv[i] - lm);
            ll += e * l2[(p0 + i) * 16 + h];
            la += e * acc2[(size_t)(p0 + i) * 1024 + (size_t)h * 64 + ld];
        }
        if (ld == 0) { sM[w] = lm; sL[w] = ll; }
        sA[w][ld] = la;
        __syncthreads();
        if (w == 0) {
            float M = fmaxf(fmaxf(sM[0], sM[1]), fmaxf(sM[2], sM[3]));
            float L = 0.f, a = 0.f;
#pragma unroll
            for (int w4 = 0; w4 < 4; ++w4) {
                float e = __expf(sM[w4] - M);
                L += e * sL[w4];
                a += e * sA[w4][ld];
            }
            acc3[((size_t)g * 16 + h) * 64 + ld] = a;
            if (ld == 0) { m3[g * 16 + h] = M; l3[g * 16 + h] = L; }
        }
    }
    grid.sync();

    // ---- stage B: Wo GEMV, block (colgroup c = b>>4, head h = b&15), 64x64 tile
    {
        int c = b >> 4, h = b & 15;
        if (t < 64) {
            float M = -1e30f;
#pragma unroll
            for (int g = 0; g < 16; ++g) M = fmaxf(M, m3[g * 16 + h]);
            float L = 0.f, a = 0.f;
#pragma unroll
            for (int g = 0; g < 16; ++g) {
                float e = __expf(m3[g * 16 + h] - M);
                L += e * l3[g * 16 + h];
                a += e * acc3[((size_t)g * 16 + h) * 64 + t];
            }
            vals[t] = a / L;
        }
        __syncthreads();
        int q = t >> 6, j = t & 63;
        float acc = 0.f;
#pragma unroll
        for (int i = 0; i < 16; ++i) {
            int r = q * 16 + i;
            acc = fmaf(vals[r], Wo[(size_t)(h * 64 + r) * EDIM + c * 64 + j], acc);
        }
        sred[q][j] = acc;
        __syncthreads();
        if (t < 64) gp1[h * EDIM + c * 64 + t] =
            sred[0][t] + sred[1][t] + sred[2][t] + sred[3][t];
    }
    grid.sync();

    // ---- stage C: residual+LN1 prologue then W1 GEMV, block (c = b>>4, r = b&15)
    {
        int c = b >> 4, r = b & 15;
        float2 ss = {0.f, 0.f};
#pragma unroll
        for (int j = 0; j < 4; ++j) {
            int i = t + 256 * j;
            float v = x[i] + bo[i];
#pragma unroll
            for (int sl = 0; sl < 16; ++sl) v += gp1[sl * EDIM + i];
            r_l[i] = v;
            ss.x += v; ss.y += v * v;
        }
        float2 sT = blockSum256_2(ss, red);   // internal barriers also publish r_l
        float mean = sT.x * (1.f / 1024.f);
        float var = sT.y * (1.f / 1024.f) - mean * mean;
        float rstd = rsqrtf(var + 1e-6f);
        if (t < 64) {
            int row = r * 64 + t;
            float hv = (r_l[row] - mean) * rstd * ln1s[row] + ln1b[row];
            vals[t] = hv;
            if (c == 0) h1[row] = hv;
        }
        __syncthreads();
        int q = t >> 6, j = t & 63;
        float acc = 0.f;
#pragma unroll
        for (int i = 0; i < 16; ++i) {
            int rr = q * 16 + i;
            acc = fmaf(vals[rr], W1[(size_t)(r * 64 + rr) * EDIM + c * 64 + j], acc);
        }
        sred[q][j] = acc;
        __syncthreads();
        if (t < 64) gp2[r * EDIM + c * 64 + t] =
            sred[0][t] + sred[1][t] + sred[2][t] + sred[3][t];
    }
    grid.sync();

    // ---- stage D: ReLU prologue then W2 GEMV, block (c = b>>4, r = b&15)
    {
        int c = b >> 4, r = b & 15;
        if (t < 64) {
            int row = r * 64 + t;
            float v = b1[row];
#pragma unroll
            for (int sl = 0; sl < 16; ++sl) v += gp2[sl * EDIM + row];
            vals[t] = fmaxf(v, 0.f);
        }
        __syncthreads();
        int q = t >> 6, j = t & 63;
        float acc = 0.f;
#pragma unroll
        for (int i = 0; i < 16; ++i) {
            int rr = q * 16 + i;
            acc = fmaf(vals[rr], W2[(size_t)(r * 64 + rr) * EDIM + c * 64 + j], acc);
        }
        sred[q][j] = acc;
        __syncthreads();
        if (t < 64) gp3[r * EDIM + c * 64 + t] =
            sred[0][t] + sred[1][t] + sred[2][t] + sred[3][t];
    }
    grid.sync();

    // ---- stage E: final residual+LN2, block 0 only
    if (b == 0) {
        float rv[4];
        float2 ss = {0.f, 0.f};
#pragma unroll
        for (int j = 0; j < 4; ++j) {
            int i = t + 256 * j;
            float v = b2[i] + h1[i];
#pragma unroll
            for (int sl = 0; sl < 16; ++sl) v += gp3[sl * EDIM + i];
            rv[j] = v;
            ss.x += v; ss.y += v * v;
        }
        float2 sT = blockSum256_2(ss, red);
        float mean = sT.x * (1.f / 1024.f);
        float var = sT.y * (1.f / 1024.f) - mean * mean;
        float rstd = rsqrtf(var + 1e-6f);
#pragma unroll
        for (int j = 0; j < 4; ++j) {
            int i = t + 256 * j;
            out[i] = (rv[j] - mean) * rstd * ln2s[i] + ln2b[i];
        }
    }
}

// ---------------- launch ----------------
extern "C" void kernel_launch(void* const* d_in, const int* in_sizes, int n_in,
                              void* d_out, int out_size, void* d_ws, size_t ws_size,
                              hipStream_t stream) {
    const float* x     = (const float*)d_in[0];
    const float* cache = (const float*)d_in[1];
    const float* Wv    = (const float*)d_in[2];
    const float* bv    = (const float*)d_in[3];
    const float* Wq    = (const float*)d_in[4];
    const float* bq    = (const float*)d_in[5];
    const float* Wk    = (const float*)d_in[6];
    const float* bk    = (const float*)d_in[7];
    const float* Wo    = (const float*)d_in[8];
    const float* bo    = (const float*)d_in[9];
    const float* W1    = (const float*)d_in[10];
    const float* b1    = (const float*)d_in[11];
    const float* W2    = (const float*)d_in[12];
    const float* b2    = (const float*)d_in[13];
    const float* ln1s  = (const float*)d_in[14];
    const float* ln1b  = (const float*)d_in[15];
    const float* ln2s  = (const float*)d_in[16];
    const float* ln2b  = (const float*)d_in[17];

    float* out = (float*)d_out;
    float* nv = out + 1024;
    float* nk = out + 1024 + (size_t)SLEN * EDIM;

    float* w    = (float*)d_ws;
    float* qkvp = w;                          // 48*1024
    float* m2   = qkvp + 48 * 1024;           // NB*16
    float* l2   = m2 + (size_t)NB * 16;       // NB*16
    float* acc2 = l2 + (size_t)NB * 16;       // NB*1024
    float* m3   = acc2 + (size_t)NB * 1024;   // 256
    float* l3   = m3 + 256;                   // 256
    float* acc3 = l3 + 256;                   // 16*1024
    float* gp1  = acc3 + 16 * 1024;           // 16*1024
    float* h1   = gp1 + 16 * 1024;            // 1024
    float* gp2  = h1 + 1024;                  // 16*1024
    float* gp3  = gp2 + 16 * 1024;            // 16*1024

    qkv_partial<<<dim3(12, 16), 256, 0, stream>>>(Wq, Wk, Wv, x, qkvp);
    attn_main<<<NB, 512, 0, stream>>>(cache, qkvp, bq, bk, bv, nv, nk, m2, l2, acc2);

    void* args[] = {
        (void*)&m2, (void*)&l2, (void*)&acc2,
        (void*)&Wo, (void*)&bo, (void*)&x,
        (void*)&ln1s, (void*)&ln1b,
        (void*)&W1, (void*)&b1, (void*)&W2, (void*)&b2,
        (void*)&ln2s, (void*)&ln2b,
        (void*)&m3, (void*)&l3, (void*)&acc3,
        (void*)&gp1, (void*)&h1, (void*)&gp2, (void*)&gp3,
        (void*)&out
    };
    hipLaunchCooperativeKernel((const void*)tail, dim3(256), dim3(256),
                               args, 0, stream);
}